// Round 12
// baseline (525.489 us; speedup 1.0000x reference)
//
#include <hip/hip_runtime.h>

#define NV 16384
#define EH 16256
#define EVV 16256
#define ED 16129
#define NE 48641
#define NT 32258
#define ND 32259
#define OUTERF 32258
#define REGK 16
#define REGN 16384

typedef unsigned int u32;
typedef unsigned short u16;

// ---------------- ws layout ----------------
static __host__ __device__ constexpr size_t al256(size_t x) { return (x + 255) & ~(size_t)255; }
static constexpr size_t OFF_ACC   = 0;                                  // acc[0..6)
static constexpr size_t OFF_R32   = 256;                                // u32[NV]
static constexpr size_t OFF_FVAL  = OFF_R32   + al256(NV * 4);          // f32[ND]
static constexpr size_t OFF_CTV   = OFF_FVAL  + al256(ND * 4);          // u16[NT]
static constexpr size_t OFF_CNTR  = OFF_CTV   + al256(NT * 2);          // u32[NV]
static constexpr size_t OFF_FRK   = OFF_CNTR  + al256(NV * 4);          // u32[ND]
static constexpr size_t OFF_FRV   = OFF_FRK   + al256(ND * 4);          // f32[ND]
static constexpr size_t OFF_DVAL  = OFF_FRV   + al256(ND * 4);          // f32[NE]
static constexpr size_t OFF_WLA   = OFF_DVAL  + al256(NE * 4);          // uint2[NE]
static constexpr size_t OFF_WLB   = OFF_WLA   + al256(NE * 8);          // uint2[NE]
static constexpr size_t OFF_RTS   = OFF_WLB   + al256(NE * 8);          // u32[NE]

__device__ __forceinline__ u32 fmap(float x) {
  u32 u = __float_as_uint(x);
  return (u & 0x80000000u) ? ~u : (u | 0x80000000u);
}
__device__ __forceinline__ float funmap(u32 m) {
  u32 u = (m & 0x80000000u) ? (m & 0x7FFFFFFFu) : ~m;
  return __uint_as_float(u);
}

__device__ __forceinline__ int findh(volatile u16* par, int x) {
  while (true) {
    int p = par[x];
    if (p == x) return x;
    int gp = par[p];
    if (gp == p) return p;
    par[x] = (u16)gp;
    x = gp;
  }
}

// edge eid -> primal endpoints
__device__ __forceinline__ void decode_pe(u32 e, int& eu, int& ev) {
  if (e < EH) { int i = (int)(e / 127u), j = (int)(e - (u32)i * 127u); eu = (i << 7) + j; ev = eu + 1; }
  else if (e < EH + EVV) { int k = (int)(e - EH); eu = k; ev = k + 128; }
  else { int k = (int)(e - EH - EVV); int i = k / 127, j = k - i * 127; eu = (i << 7) + j; ev = eu + 129; }
}
// edge eid -> dual faces
__device__ __forceinline__ void decode_df(u32 e, int& fa, int& fb) {
  if (e < EH) { int i = (int)(e / 127u), j = (int)(e - (u32)i * 127u);
    fa = (i < 127) ? (ED + i * 127 + j) : OUTERF;
    fb = (i >= 1) ? ((i - 1) * 127 + j) : OUTERF; }
  else if (e < EH + EVV) { int k = (int)(e - EH); int i = k >> 7, j = k & 127;
    fa = (j < 127) ? (i * 127 + j) : OUTERF;
    fb = (j >= 1) ? (ED + i * 127 + (j - 1)) : OUTERF; }
  else { int k = (int)(e - EH - EVV); int i = k / 127, j = k - i * 127;
    fa = i * 127 + j; fb = ED + i * 127 + j; }
}

// ---------------- K0: init ----------------
// acc: F[0]=sum dv(all edges), F[1]=sum beta, U[2]=max beta(fmap), F[3]=sum fval(faces)
__global__ void k_init(float* accF, u32* r32) {
  int i = blockIdx.x * 256 + threadIdx.x;
  if (i < 6) accF[i] = 0.f;
  if (i < NV) r32[i] = 0u;
}

// ---------------- K1: vertex ranks (ascending beta, id tiebreak) ----------------
__global__ void k_rankv(const float* __restrict__ beta, u32* r32) {
  int v = blockIdx.x * 256 + threadIdx.x;
  int c = blockIdx.y;
  float bv = beta[v];
  int u0 = c << 10;
  int cnt = 0;
#pragma unroll 8
  for (int u = u0; u < u0 + 1024; ++u) {
    float bu = beta[u];
    cnt += (bu < bv || (bu == bv && u < v)) ? 1 : 0;
  }
  if (cnt) atomicAdd(&r32[v], (u32)cnt);
}

// ---------------- K2: face values + crit vertex + reductions ----------------
__global__ void k_build(const float* __restrict__ beta, const u32* __restrict__ r32,
                        float* fval, u16* ctv, float* accF, u32* accU) {
  __shared__ float ls[4], lm[4];
  int bid = blockIdx.x, tid = threadIdx.x;
  if (bid < 64) {
    int v = (bid << 8) + tid;
    float b = beta[v];
    float s = b, m = b;
    for (int off = 32; off >= 1; off >>= 1) {
      s += __shfl_down(s, off);
      m = fmaxf(m, __shfl_down(m, off));
    }
    int wid = tid >> 6;
    if ((tid & 63) == 0) { ls[wid] = s; lm[wid] = m; }
    __syncthreads();
    if (tid == 0) {
      s = ls[0] + ls[1] + ls[2] + ls[3];
      m = fmaxf(fmaxf(lm[0], lm[1]), fmaxf(lm[2], lm[3]));
      atomicAdd(&accF[1], s);
      atomicMax(&accU[2], fmap(m));
    }
  } else {
    int t = ((bid - 64) << 8) + tid;
    float c = 0.f;
    if (t < NT) {
      int i, j, v0, v1, v2;
      if (t < ED) { i = t / 127; j = t - i * 127; v0 = (i << 7) + j; v1 = v0 + 128; v2 = v0 + 129; } // L
      else { int u = t - ED; i = u / 127; j = u - i * 127; v0 = (i << 7) + j; v1 = v0 + 1; v2 = v0 + 129; } // U
      u32 r0 = r32[v0], r1 = r32[v1], r2 = r32[v2];
      int crit = v0; u32 rm = r0;
      if (r1 < rm) { rm = r1; crit = v1; }
      if (r2 < rm) { rm = r2; crit = v2; }
      float fv = -beta[crit];
      fval[t] = fv;
      ctv[t] = (u16)crit;
      c = fv;
      if (t == 0) fval[OUTERF] = __builtin_inff();
    }
    for (int off = 32; off >= 1; off >>= 1) c += __shfl_down(c, off);
    int wid = tid >> 6;
    if ((tid & 63) == 0) ls[wid] = c;
    __syncthreads();
    if (tid == 0) atomicAdd(&accF[3], ls[0] + ls[1] + ls[2] + ls[3]);
  }
}

// ---------------- K3a: per-vertex crit-face counts into rank buckets ----------------
__global__ void k_cntface(const u16* __restrict__ ctv, const u32* __restrict__ r32, u32* cntR) {
  int v = blockIdx.x * 256 + threadIdx.x;
  int i = v >> 7, j = v & 127;
  int cnt = 0;
  if (i < 127 && j < 127) cnt += (ctv[i * 127 + j] == v);
  if (i >= 1 && j < 127)  cnt += (ctv[(i - 1) * 127 + j] == v);
  if (i >= 1 && j >= 1)   cnt += (ctv[(i - 1) * 127 + (j - 1)] == v);
  if (i < 127 && j < 127) cnt += (ctv[ED + i * 127 + j] == v);
  if (i < 127 && j >= 1)  cnt += (ctv[ED + i * 127 + (j - 1)] == v);
  if (i >= 1 && j >= 1)   cnt += (ctv[ED + (i - 1) * 127 + (j - 1)] == v);
  cntR[r32[v]] = (u32)cnt;
}

// ---------------- K3b: exclusive scan over NV rank buckets (+1: outer face = rank 0) ----------------
__global__ __launch_bounds__(1024) void k_scanR(u32* cntR) {
  __shared__ u32 wsum[16];
  int tid = threadIdx.x;
  u32 loc[16]; u32 s = 0;
#pragma unroll
  for (int k = 0; k < 16; ++k) { u32 c = cntR[(tid << 4) + k]; loc[k] = s; s += c; }
  int lane = tid & 63, wid = tid >> 6;
  u32 incl = s;
  for (int off = 1; off < 64; off <<= 1) {
    u32 o = __shfl_up(incl, off);
    if (lane >= off) incl += o;
  }
  if (lane == 63) wsum[wid] = incl;
  __syncthreads();
  u32 wbase = 0;
  for (int w = 0; w < wid; ++w) wbase += wsum[w];
  u32 base = wbase + incl - s + 1;
#pragma unroll
  for (int k = 0; k < 16; ++k) cntR[(tid << 4) + k] = base + loc[k];
}

// ---------------- K3c: face ranks + rank->value table ----------------
__global__ void k_facerank(const u16* __restrict__ ctv, const u32* __restrict__ r32,
                           const u32* __restrict__ startsR, const float* __restrict__ fval,
                           u32* frk, float* frv) {
  int g = blockIdx.x * 256 + threadIdx.x;
  if (g == 0) { frk[OUTERF] = 0u; frv[0] = __builtin_inff(); }
  if (g >= NT) return;
  int v = ctv[g];
  int i = v >> 7, j = v & 127;
  int local = 0, f;
  if (i < 127 && j < 127) { f = i * 127 + j;             local += (f < g && ctv[f] == v); }
  if (i >= 1 && j < 127)  { f = (i - 1) * 127 + j;       local += (f < g && ctv[f] == v); }
  if (i >= 1 && j >= 1)   { f = (i - 1) * 127 + (j - 1); local += (f < g && ctv[f] == v); }
  if (i < 127 && j < 127) { f = ED + i * 127 + j;        local += (f < g && ctv[f] == v); }
  if (i < 127 && j >= 1)  { f = ED + i * 127 + (j - 1);  local += (f < g && ctv[f] == v); }
  if (i >= 1 && j >= 1)   { f = ED + (i - 1) * 127 + (j - 1); local += (f < g && ctv[f] == v); }
  u32 rk = startsR[r32[v]] + (u32)local;
  frk[g] = rk;
  frv[rk] = fval[g];
}

// ---------------- K4: edge values + initial worklist records + total sum ----------------
// record: x = frk[fa] | frk[fb]<<16 (dual endpoints in rank space)
//         y = (rr<<17) | e          (filtration key: descending f == ascending rr, eid tiebreak)
__global__ void k_edges(const float* __restrict__ beta, const u32* __restrict__ r32,
                        const u32* __restrict__ frk,
                        float* dvals, uint2* wl0, float* accF) {
  int e = blockIdx.x * 256 + threadIdx.x;
  float dv = 0.f;
  if (e < NE) {
    int eu, ev; decode_pe((u32)e, eu, ev);
    int fa, fb; decode_df((u32)e, fa, fb);
    u32 ru = r32[eu], rv = r32[ev];
    u32 rr = min(ru, rv);
    int cv = (ru <= rv) ? eu : ev;
    dv = -beta[cv];
    dvals[e] = dv;
    wl0[e] = make_uint2(frk[fa] | (frk[fb] << 16), (rr << 17) | (u32)e);
  }
  float ds = dv;
  for (int off = 32; off >= 1; off >>= 1) ds += __shfl_down(ds, off);
  if ((threadIdx.x & 63) == 0) atomicAdd(&accF[0], ds);
}

// ---------------- K5: unified dual Kruskal (maxST + pairing + output) ----------------
// Full dual graph, ascending key (descending f). CLAIM-BOTH / WIN-YOUNGER (proven
// round 10): P1 claims mt[h(ra)] AND mt[h(rb)] with the root pair frozen; P2 commits
// iff the edge holds slot h(y), y = max(ra,rb); losers requeue; ra==rb drops.
// Round 0: roots == record endpoints (all singletons) -> no finds, no rts traffic.
// Tail (n <= REGN): worklist lives in REGISTERS (prR/keyR/dvR, live-bitmask), same
// P1/P2/P3 protocol as pure-LDS sub-rounds with zero global traffic.
__global__ __launch_bounds__(1024) void k_dual(
    uint2* __restrict__ wlA, uint2* __restrict__ wlB, u32* __restrict__ rts,
    const float* __restrict__ dvals, const float* __restrict__ frv,
    const float* __restrict__ accF, const u32* __restrict__ accU, float* out) {
  __shared__ u16 par[ND + 1];     // 64.5 KB
  __shared__ u32 mt[16384];       // 64 KB
  __shared__ int nCur, nNxt;
  __shared__ int flags[2];
  __shared__ float redS[16], redM[16];
  int tid = threadIdx.x, lane = tid & 63;
  {
    u32* p32 = (u32*)par;
    for (int v = tid; v < (ND + 1) / 2; v += 1024)
      p32[v] = ((2u * v + 1) << 16) | (2u * v);
  }
  for (int h = tid; h < 16384; h += 1024) mt[h] = 0xFFFFFFFFu;
  if (tid == 0) { nNxt = 0; flags[0] = 0; flags[1] = 0; }
  float wD = 0.f, lmax = 0.f;
  __syncthreads();
  uint2* cur = wlA;
  uint2* nxt = wlB;
  int n = NE;
  for (int round = 0; round < 50000 && n > 0; ++round) {
    if (n <= REGN) break;                          // -> register-resident tail
    bool r0 = (round == 0);
    // P1: find roots (skip round 0), freeze pair in rts, claim BOTH slots
    for (int i0 = 0; i0 < n; i0 += 1024) {
      int i = i0 + tid;
      if (i < n) {
        uint2 rec = cur[i];
        int ra, rb;
        if (r0) { ra = (int)(rec.x & 0xFFFFu); rb = (int)(rec.x >> 16); }
        else {
          ra = findh((volatile u16*)par, (int)(rec.x & 0xFFFFu));
          rb = findh((volatile u16*)par, (int)(rec.x >> 16));
        }
        if (ra == rb) {
          if (!r0) rts[i] = 0xFFFFFFFFu;           // cycle edge: drop
        } else {
          if (!r0) rts[i] = (u32)ra | ((u32)rb << 16);
          atomicMin(&mt[(u32)ra & 16383u], rec.y);
          atomicMin(&mt[(u32)rb & 16383u], rec.y);
        }
      }
    }
    __syncthreads();
    // P2: win-younger commits + hook; losers requeue (wave-aggregated)
    for (int i0 = 0; i0 < n; i0 += 1024) {
      int i = i0 + tid;
      bool active = i < n;
      u32 pr = 0xFFFFFFFFu, key = 0;
      if (active) {
        uint2 rec = cur[i];
        key = rec.y;
        pr = r0 ? rec.x : rts[i];
      }
      bool pend = active && (pr != 0xFFFFFFFFu);
      u32 y = 0, o = 0;
      bool win = false;
      if (pend) {
        u32 a = pr & 0xFFFFu, b = pr >> 16;
        y = max(a, b); o = min(a, b);
        win = (mt[y & 16383u] == key);
      }
      if (win) {
        par[y] = (u16)o;                           // exact sequential merge
        float dv = dvals[key & 0x1FFFFu];
        wD += dv;
        lmax = fmaxf(lmax, frv[y] - dv);           // bar: birth frv[y], death dv
      }
      bool req = pend && !win;
      unsigned long long mk = __ballot(req);
      int base = 0;
      if (lane == 0) {
        int c = __popcll(mk);
        if (c) base = atomicAdd(&nNxt, c);
      }
      base = __shfl(base, 0);
      if (req) {
        int pos = base + __popcll(mk & ((1ull << lane) - 1ull));
        nxt[pos] = make_uint2(pr, key);            // requeue with current roots
      }
    }
    __syncthreads();
    // P3: full claim reset + compression + counter swap
    for (int h = tid; h < 16384; h += 1024) mt[h] = 0xFFFFFFFFu;
    for (int v = tid; v < ND; v += 1024) {
      int p = par[v]; int pp = par[p];
      if (p != pp) par[v] = (u16)pp;
    }
    if (tid == 0) { nCur = nNxt; nNxt = 0; }
    __syncthreads();
    n = nCur;
    uint2* s = cur; cur = nxt; nxt = s;
  }
  // ---- register-resident tail: same protocol, pure-LDS sub-rounds ----
  if (n > 0) {
    u32 prR[REGK], keyR[REGK];
    float dvR[REGK];
    u32 live = 0;
#pragma unroll
    for (int k = 0; k < REGK; ++k) {
      int i = tid + (k << 10);
      prR[k] = 0; keyR[k] = 0; dvR[k] = 0.f;
      if (i < n) {
        uint2 rec = cur[i];
        prR[k] = rec.x; keyR[k] = rec.y;
        dvR[k] = dvals[rec.y & 0x1FFFFu];
        live |= (1u << k);
      }
    }
    for (int sr = 0; sr < 100000; ++sr) {
      u32 claimed = 0;
      // P1: refresh roots, claim both slots
#pragma unroll
      for (int k = 0; k < REGK; ++k) {
        if ((live >> k) & 1u) {
          int ra = findh((volatile u16*)par, (int)(prR[k] & 0xFFFFu));
          int rb = findh((volatile u16*)par, (int)(prR[k] >> 16));
          if (ra == rb) {
            live &= ~(1u << k);                    // cycle edge: drop
          } else {
            prR[k] = (u32)ra | ((u32)rb << 16);
            claimed |= (1u << k);
            atomicMin(&mt[(u32)ra & 16383u], keyR[k]);
            atomicMin(&mt[(u32)rb & 16383u], keyR[k]);
          }
        }
      }
      __syncthreads();
      // P2: win-younger commits
#pragma unroll
      for (int k = 0; k < REGK; ++k) {
        if ((claimed >> k) & 1u) {
          u32 a = prR[k] & 0xFFFFu, b = prR[k] >> 16;
          u32 y = max(a, b), o = min(a, b);
          if (mt[y & 16383u] == keyR[k]) {
            par[y] = (u16)o;
            wD += dvR[k];
            lmax = fmaxf(lmax, frv[y] - dvR[k]);
            live &= ~(1u << k);
          }
        }
      }
      if (live) flags[sr & 1] = 1;                 // benign race: all store 1
      __syncthreads();
      // P3: reset claimed slots; read continue-flag; prep next flag
#pragma unroll
      for (int k = 0; k < REGK; ++k) {
        if ((claimed >> k) & 1u) {
          mt[(prR[k] & 0xFFFFu) & 16383u] = 0xFFFFFFFFu;
          mt[(prR[k] >> 16) & 16383u] = 0xFFFFFFFFu;
        }
      }
      int cont = flags[sr & 1];
      if (tid == 0) flags[(sr + 1) & 1] = 0;
      __syncthreads();
      if (!cont) break;
    }
  }
  // reduce W_D (sum) and lmax (max), assemble output
  for (int off = 32; off >= 1; off >>= 1) {
    wD += __shfl_down(wD, off);
    lmax = fmaxf(lmax, __shfl_down(lmax, off));
  }
  if (lane == 0) { redS[tid >> 6] = wD; redM[tid >> 6] = lmax; }
  __syncthreads();
  if (tid == 0) {
    float s = 0.f, m = 0.f;
    for (int w = 0; w < 16; ++w) { s += redS[w]; m = fmaxf(m, redM[w]); }
    float wmst = accF[0] - s;                     // primal MST via tree-cotree duality
    float loss0 = wmst + accF[1] - funmap(accU[2]);
    float sum1 = accF[3] - s;                     // sum of dim-1 bars (closed form)
    out[0] = loss0 + sum1 - m;
  }
}

extern "C" void kernel_launch(void* const* d_in, const int* in_sizes, int n_in,
                              void* d_out, int out_size, void* d_ws, size_t ws_size,
                              hipStream_t stream) {
  const float* beta = (const float*)d_in[0];
  float* out = (float*)d_out;
  char* ws = (char*)d_ws;
  float* accF = (float*)(ws + OFF_ACC);
  u32*   accU = (u32*)(ws + OFF_ACC);
  u32* r32 = (u32*)(ws + OFF_R32);
  float* fval = (float*)(ws + OFF_FVAL);
  u16* ctv = (u16*)(ws + OFF_CTV);
  u32* cntR = (u32*)(ws + OFF_CNTR);
  u32* frk = (u32*)(ws + OFF_FRK);
  float* frv = (float*)(ws + OFF_FRV);
  float* dvals = (float*)(ws + OFF_DVAL);
  uint2* wlA = (uint2*)(ws + OFF_WLA);
  uint2* wlB = (uint2*)(ws + OFF_WLB);
  u32* rts = (u32*)(ws + OFF_RTS);

  hipLaunchKernelGGL(k_init, dim3(64), dim3(256), 0, stream, accF, r32);
  hipLaunchKernelGGL(k_rankv, dim3(64, 16), dim3(256), 0, stream, beta, r32);
  hipLaunchKernelGGL(k_build, dim3(191), dim3(256), 0, stream, beta, r32, fval, ctv, accF, accU);
  hipLaunchKernelGGL(k_cntface, dim3(64), dim3(256), 0, stream, ctv, r32, cntR);
  hipLaunchKernelGGL(k_scanR, dim3(1), dim3(1024), 0, stream, cntR);
  hipLaunchKernelGGL(k_facerank, dim3(127), dim3(256), 0, stream, ctv, r32, cntR, fval, frk, frv);
  hipLaunchKernelGGL(k_edges, dim3(191), dim3(256), 0, stream, beta, r32, frk, dvals, wlA, accF);
  hipLaunchKernelGGL(k_dual, dim3(1), dim3(1024), 0, stream, wlA, wlB, rts, dvals, frv, accF, accU, out);
}

// Round 13
// 386.123 us; speedup vs baseline: 1.3609x; 1.3609x over previous
//
#include <hip/hip_runtime.h>

#define NV 16384
#define EH 16256
#define EVV 16256
#define ED 16129
#define NE 48641
#define NT 32258
#define ND 32259
#define OUTERF 32258
#define TAILN 4096

typedef unsigned int u32;
typedef unsigned short u16;

// ---------------- ws layout ----------------
static __host__ __device__ constexpr size_t al256(size_t x) { return (x + 255) & ~(size_t)255; }
static constexpr size_t OFF_ACC   = 0;                                  // acc[0..6)
static constexpr size_t OFF_R32   = 256;                                // u32[NV]
static constexpr size_t OFF_FVAL  = OFF_R32   + al256(NV * 4);          // f32[ND]
static constexpr size_t OFF_CTV   = OFF_FVAL  + al256(ND * 4);          // u16[NT]
static constexpr size_t OFF_CNTR  = OFF_CTV   + al256(NT * 2);          // u32[NV]
static constexpr size_t OFF_FRK   = OFF_CNTR  + al256(NV * 4);          // u32[ND]
static constexpr size_t OFF_FRV   = OFF_FRK   + al256(ND * 4);          // f32[ND]
static constexpr size_t OFF_DVAL  = OFF_FRV   + al256(ND * 4);          // f32[NE]
static constexpr size_t OFF_WLA   = OFF_DVAL  + al256(NE * 4);          // uint2[NE]
static constexpr size_t OFF_WLB   = OFF_WLA   + al256(NE * 8);          // uint2[NE]
static constexpr size_t OFF_RTS   = OFF_WLB   + al256(NE * 8);          // u32[NE]

__device__ __forceinline__ u32 fmap(float x) {
  u32 u = __float_as_uint(x);
  return (u & 0x80000000u) ? ~u : (u | 0x80000000u);
}
__device__ __forceinline__ float funmap(u32 m) {
  u32 u = (m & 0x80000000u) ? (m & 0x7FFFFFFFu) : ~m;
  return __uint_as_float(u);
}

__device__ __forceinline__ int findh(volatile u16* par, int x) {
  while (true) {
    int p = par[x];
    if (p == x) return x;
    int gp = par[p];
    if (gp == p) return p;
    par[x] = (u16)gp;
    x = gp;
  }
}

// edge eid -> primal endpoints
__device__ __forceinline__ void decode_pe(u32 e, int& eu, int& ev) {
  if (e < EH) { int i = (int)(e / 127u), j = (int)(e - (u32)i * 127u); eu = (i << 7) + j; ev = eu + 1; }
  else if (e < EH + EVV) { int k = (int)(e - EH); eu = k; ev = k + 128; }
  else { int k = (int)(e - EH - EVV); int i = k / 127, j = k - i * 127; eu = (i << 7) + j; ev = eu + 129; }
}
// edge eid -> dual faces
__device__ __forceinline__ void decode_df(u32 e, int& fa, int& fb) {
  if (e < EH) { int i = (int)(e / 127u), j = (int)(e - (u32)i * 127u);
    fa = (i < 127) ? (ED + i * 127 + j) : OUTERF;
    fb = (i >= 1) ? ((i - 1) * 127 + j) : OUTERF; }
  else if (e < EH + EVV) { int k = (int)(e - EH); int i = k >> 7, j = k & 127;
    fa = (j < 127) ? (i * 127 + j) : OUTERF;
    fb = (j >= 1) ? (ED + i * 127 + (j - 1)) : OUTERF; }
  else { int k = (int)(e - EH - EVV); int i = k / 127, j = k - i * 127;
    fa = i * 127 + j; fb = ED + i * 127 + j; }
}

// ---------------- K0: init ----------------
// acc: F[0]=sum dv(all edges), F[1]=sum beta, U[2]=max beta(fmap), F[3]=sum fval(faces)
__global__ void k_init(float* accF, u32* r32) {
  int i = blockIdx.x * 256 + threadIdx.x;
  if (i < 6) accF[i] = 0.f;
  if (i < NV) r32[i] = 0u;
}

// ---------------- K1: vertex ranks (ascending beta, id tiebreak) ----------------
__global__ void k_rankv(const float* __restrict__ beta, u32* r32) {
  int v = blockIdx.x * 256 + threadIdx.x;
  int c = blockIdx.y;
  float bv = beta[v];
  int u0 = c << 10;
  int cnt = 0;
#pragma unroll 8
  for (int u = u0; u < u0 + 1024; ++u) {
    float bu = beta[u];
    cnt += (bu < bv || (bu == bv && u < v)) ? 1 : 0;
  }
  if (cnt) atomicAdd(&r32[v], (u32)cnt);
}

// ---------------- K2: face values + crit vertex + reductions ----------------
__global__ void k_build(const float* __restrict__ beta, const u32* __restrict__ r32,
                        float* fval, u16* ctv, float* accF, u32* accU) {
  __shared__ float ls[4], lm[4];
  int bid = blockIdx.x, tid = threadIdx.x;
  if (bid < 64) {
    int v = (bid << 8) + tid;
    float b = beta[v];
    float s = b, m = b;
    for (int off = 32; off >= 1; off >>= 1) {
      s += __shfl_down(s, off);
      m = fmaxf(m, __shfl_down(m, off));
    }
    int wid = tid >> 6;
    if ((tid & 63) == 0) { ls[wid] = s; lm[wid] = m; }
    __syncthreads();
    if (tid == 0) {
      s = ls[0] + ls[1] + ls[2] + ls[3];
      m = fmaxf(fmaxf(lm[0], lm[1]), fmaxf(lm[2], lm[3]));
      atomicAdd(&accF[1], s);
      atomicMax(&accU[2], fmap(m));
    }
  } else {
    int t = ((bid - 64) << 8) + tid;
    float c = 0.f;
    if (t < NT) {
      int i, j, v0, v1, v2;
      if (t < ED) { i = t / 127; j = t - i * 127; v0 = (i << 7) + j; v1 = v0 + 128; v2 = v0 + 129; } // L
      else { int u = t - ED; i = u / 127; j = u - i * 127; v0 = (i << 7) + j; v1 = v0 + 1; v2 = v0 + 129; } // U
      u32 r0 = r32[v0], r1 = r32[v1], r2 = r32[v2];
      int crit = v0; u32 rm = r0;
      if (r1 < rm) { rm = r1; crit = v1; }
      if (r2 < rm) { rm = r2; crit = v2; }
      float fv = -beta[crit];
      fval[t] = fv;
      ctv[t] = (u16)crit;
      c = fv;
      if (t == 0) fval[OUTERF] = __builtin_inff();
    }
    for (int off = 32; off >= 1; off >>= 1) c += __shfl_down(c, off);
    int wid = tid >> 6;
    if ((tid & 63) == 0) ls[wid] = c;
    __syncthreads();
    if (tid == 0) atomicAdd(&accF[3], ls[0] + ls[1] + ls[2] + ls[3]);
  }
}

// ---------------- K3a: per-vertex crit-face counts into rank buckets ----------------
__global__ void k_cntface(const u16* __restrict__ ctv, const u32* __restrict__ r32, u32* cntR) {
  int v = blockIdx.x * 256 + threadIdx.x;
  int i = v >> 7, j = v & 127;
  int cnt = 0;
  if (i < 127 && j < 127) cnt += (ctv[i * 127 + j] == v);
  if (i >= 1 && j < 127)  cnt += (ctv[(i - 1) * 127 + j] == v);
  if (i >= 1 && j >= 1)   cnt += (ctv[(i - 1) * 127 + (j - 1)] == v);
  if (i < 127 && j < 127) cnt += (ctv[ED + i * 127 + j] == v);
  if (i < 127 && j >= 1)  cnt += (ctv[ED + i * 127 + (j - 1)] == v);
  if (i >= 1 && j >= 1)   cnt += (ctv[ED + (i - 1) * 127 + (j - 1)] == v);
  cntR[r32[v]] = (u32)cnt;
}

// ---------------- K3b: exclusive scan over NV rank buckets (+1: outer face = rank 0) ----------------
__global__ __launch_bounds__(1024) void k_scanR(u32* cntR) {
  __shared__ u32 wsum[16];
  int tid = threadIdx.x;
  u32 loc[16]; u32 s = 0;
#pragma unroll
  for (int k = 0; k < 16; ++k) { u32 c = cntR[(tid << 4) + k]; loc[k] = s; s += c; }
  int lane = tid & 63, wid = tid >> 6;
  u32 incl = s;
  for (int off = 1; off < 64; off <<= 1) {
    u32 o = __shfl_up(incl, off);
    if (lane >= off) incl += o;
  }
  if (lane == 63) wsum[wid] = incl;
  __syncthreads();
  u32 wbase = 0;
  for (int w = 0; w < wid; ++w) wbase += wsum[w];
  u32 base = wbase + incl - s + 1;
#pragma unroll
  for (int k = 0; k < 16; ++k) cntR[(tid << 4) + k] = base + loc[k];
}

// ---------------- K3c: face ranks + rank->value table ----------------
__global__ void k_facerank(const u16* __restrict__ ctv, const u32* __restrict__ r32,
                           const u32* __restrict__ startsR, const float* __restrict__ fval,
                           u32* frk, float* frv) {
  int g = blockIdx.x * 256 + threadIdx.x;
  if (g == 0) { frk[OUTERF] = 0u; frv[0] = __builtin_inff(); }
  if (g >= NT) return;
  int v = ctv[g];
  int i = v >> 7, j = v & 127;
  int local = 0, f;
  if (i < 127 && j < 127) { f = i * 127 + j;             local += (f < g && ctv[f] == v); }
  if (i >= 1 && j < 127)  { f = (i - 1) * 127 + j;       local += (f < g && ctv[f] == v); }
  if (i >= 1 && j >= 1)   { f = (i - 1) * 127 + (j - 1); local += (f < g && ctv[f] == v); }
  if (i < 127 && j < 127) { f = ED + i * 127 + j;        local += (f < g && ctv[f] == v); }
  if (i < 127 && j >= 1)  { f = ED + i * 127 + (j - 1);  local += (f < g && ctv[f] == v); }
  if (i >= 1 && j >= 1)   { f = ED + (i - 1) * 127 + (j - 1); local += (f < g && ctv[f] == v); }
  u32 rk = startsR[r32[v]] + (u32)local;
  frk[g] = rk;
  frv[rk] = fval[g];
}

// ---------------- K4: edge values + initial worklist records + total sum ----------------
// record: x = frk[fa] | frk[fb]<<16 (dual endpoints in rank space)
//         y = (rr<<17) | e          (filtration key: descending f == ascending rr, eid tiebreak)
__global__ void k_edges(const float* __restrict__ beta, const u32* __restrict__ r32,
                        const u32* __restrict__ frk,
                        float* dvals, uint2* wl0, float* accF) {
  int e = blockIdx.x * 256 + threadIdx.x;
  float dv = 0.f;
  if (e < NE) {
    int eu, ev; decode_pe((u32)e, eu, ev);
    int fa, fb; decode_df((u32)e, fa, fb);
    u32 ru = r32[eu], rv = r32[ev];
    u32 rr = min(ru, rv);
    int cv = (ru <= rv) ? eu : ev;
    dv = -beta[cv];
    dvals[e] = dv;
    wl0[e] = make_uint2(frk[fa] | (frk[fb] << 16), (rr << 17) | (u32)e);
  }
  float ds = dv;
  for (int off = 32; off >= 1; off >>= 1) ds += __shfl_down(ds, off);
  if ((threadIdx.x & 63) == 0) atomicAdd(&accF[0], ds);
}

// ---------------- K5: unified dual Kruskal (maxST + pairing + output) ----------------
// Full dual graph, ascending key (descending f). CLAIM-BOTH / WIN-YOUNGER (proven
// round 10): P1 claims mt[h(ra)] AND mt[h(rb)] with the root pair frozen; P2 commits
// iff the edge holds slot h(y), y = max(ra,rb); losers requeue; ra==rb drops.
// Round 0: roots == record endpoints (all singletons) -> no finds, no rts traffic.
// Tail (n <= TAILN): worklist moves to LDS (wlL, 32 KB); sub-rounds have ZERO
// global traffic (dead = x sentinel, no compaction; frozen pairs in a static
// 4-reg array; claimed-slot-only mt reset; ping-pong flag termination).
__global__ __launch_bounds__(1024) void k_dual(
    uint2* __restrict__ wlA, uint2* __restrict__ wlB, u32* __restrict__ rts,
    const float* __restrict__ dvals, const float* __restrict__ frv,
    const float* __restrict__ accF, const u32* __restrict__ accU, float* out) {
  __shared__ u16 par[ND + 1];     // 64520 B
  __shared__ u32 mt[16384];       // 65536 B
  __shared__ uint2 wlL[TAILN];    // 32768 B  (total 162824 B <= 160 KiB)
  __shared__ int nCur, nNxt;
  __shared__ int flags[2];
  __shared__ float redS[16], redM[16];
  int tid = threadIdx.x, lane = tid & 63;
  {
    u32* p32 = (u32*)par;
    for (int v = tid; v < (ND + 1) / 2; v += 1024)
      p32[v] = ((2u * v + 1) << 16) | (2u * v);
  }
  for (int h = tid; h < 16384; h += 1024) mt[h] = 0xFFFFFFFFu;
  if (tid == 0) { nNxt = 0; flags[0] = 0; flags[1] = 0; }
  float wD = 0.f, lmax = 0.f;
  __syncthreads();
  uint2* cur = wlA;
  uint2* nxt = wlB;
  int n = NE;
  // ---- main loop: global worklist while n > TAILN ----
  for (int round = 0; round < 50000 && n > TAILN; ++round) {
    bool r0 = (round == 0);
    // P1: find roots (skip round 0: all singletons), freeze pair, claim BOTH slots
    for (int i0 = 0; i0 < n; i0 += 1024) {
      int i = i0 + tid;
      if (i < n) {
        uint2 rec = cur[i];
        int ra, rb;
        if (r0) { ra = (int)(rec.x & 0xFFFFu); rb = (int)(rec.x >> 16); }
        else {
          ra = findh((volatile u16*)par, (int)(rec.x & 0xFFFFu));
          rb = findh((volatile u16*)par, (int)(rec.x >> 16));
        }
        if (ra == rb) {
          if (!r0) rts[i] = 0xFFFFFFFFu;           // cycle edge: drop
        } else {
          if (!r0) rts[i] = (u32)ra | ((u32)rb << 16);
          atomicMin(&mt[(u32)ra & 16383u], rec.y);
          atomicMin(&mt[(u32)rb & 16383u], rec.y);
        }
      }
    }
    __syncthreads();
    // P2: win-younger commits + hook; losers requeue (wave-aggregated)
    for (int i0 = 0; i0 < n; i0 += 1024) {
      int i = i0 + tid;
      bool active = i < n;
      u32 pr = 0xFFFFFFFFu, key = 0;
      if (active) {
        uint2 rec = cur[i];
        key = rec.y;
        pr = r0 ? rec.x : rts[i];
      }
      bool pend = active && (pr != 0xFFFFFFFFu);
      u32 y = 0, o = 0;
      bool win = false;
      if (pend) {
        u32 a = pr & 0xFFFFu, b = pr >> 16;
        y = max(a, b); o = min(a, b);
        win = (mt[y & 16383u] == key);
      }
      if (win) {
        par[y] = (u16)o;                           // exact sequential merge
        float dv = dvals[key & 0x1FFFFu];
        wD += dv;
        lmax = fmaxf(lmax, frv[y] - dv);           // bar: birth frv[y], death dv
      }
      bool req = pend && !win;
      unsigned long long mk = __ballot(req);
      int base = 0;
      if (lane == 0) {
        int c = __popcll(mk);
        if (c) base = atomicAdd(&nNxt, c);
      }
      base = __shfl(base, 0);
      if (req) {
        int pos = base + __popcll(mk & ((1ull << lane) - 1ull));
        nxt[pos] = make_uint2(pr, key);            // requeue with current roots
      }
    }
    __syncthreads();
    // P3: adaptive claim reset + compression + counter swap (one barrier)
    if (!r0 && n <= 6144) {
      for (int i0 = 0; i0 < n; i0 += 1024) {
        int i = i0 + tid;
        if (i < n) {
          u32 pr = rts[i];
          if (pr != 0xFFFFFFFFu) {
            mt[(pr & 0xFFFFu) & 16383u] = 0xFFFFFFFFu;
            mt[(pr >> 16) & 16383u] = 0xFFFFFFFFu;
          }
        }
      }
    } else {
      for (int h = tid; h < 16384; h += 1024) mt[h] = 0xFFFFFFFFu;
    }
    for (int v = tid; v < ND; v += 1024) {
      int p = par[v]; int pp = par[p];
      if (p != pp) par[v] = (u16)pp;
    }
    if (tid == 0) { nCur = nNxt; nNxt = 0; }
    __syncthreads();
    n = nCur;
    uint2* s = cur; cur = nxt; nxt = s;
  }
  // ---- LDS-resident tail: same protocol, zero global traffic ----
  if (n > 0) {
    for (int i = tid; i < n; i += 1024) wlL[i] = cur[i];
    __syncthreads();
    int nL = n;
    for (int sr = 0; sr < 100000; ++sr) {
      u32 prc[4];
      // P1: find roots from (possibly refreshed) endpoints, freeze, claim both
#pragma unroll
      for (int k = 0; k < 4; ++k) {
        prc[k] = 0xFFFFFFFFu;
        int i = tid + (k << 10);
        if (i < nL) {
          uint2 rec = wlL[i];
          if (rec.x != 0xFFFFFFFFu) {
            int ra = findh((volatile u16*)par, (int)(rec.x & 0xFFFFu));
            int rb = findh((volatile u16*)par, (int)(rec.x >> 16));
            if (ra == rb) {
              wlL[i].x = 0xFFFFFFFFu;              // cycle edge: dead
            } else {
              u32 pr = (u32)ra | ((u32)rb << 16);
              prc[k] = pr;
              wlL[i].x = pr;                       // frozen roots (= requeue form)
              atomicMin(&mt[(u32)ra & 16383u], rec.y);
              atomicMin(&mt[(u32)rb & 16383u], rec.y);
            }
          }
        }
      }
      __syncthreads();
      // P2: win-younger commits; survivors stay live
      bool any = false;
#pragma unroll
      for (int k = 0; k < 4; ++k) {
        if (prc[k] != 0xFFFFFFFFu) {
          int i = tid + (k << 10);
          u32 key = wlL[i].y;
          u32 a = prc[k] & 0xFFFFu, b = prc[k] >> 16;
          u32 y = max(a, b), o = min(a, b);
          if (mt[y & 16383u] == key) {
            par[y] = (u16)o;
            float dv = dvals[key & 0x1FFFFu];
            wD += dv;
            lmax = fmaxf(lmax, frv[y] - dv);
            wlL[i].x = 0xFFFFFFFFu;                // committed: dead
          } else {
            any = true;
          }
        }
      }
      if (any) flags[(sr + 1) & 1] = 1;            // benign multi-store of 1
      __syncthreads();
      // P3: reset claimed slots (committed AND surviving); termination check
#pragma unroll
      for (int k = 0; k < 4; ++k) {
        if (prc[k] != 0xFFFFFFFFu) {
          mt[(prc[k] & 0xFFFFu) & 16383u] = 0xFFFFFFFFu;
          mt[(prc[k] >> 16) & 16383u] = 0xFFFFFFFFu;
        }
      }
      int cont = flags[(sr + 1) & 1];
      if (tid == 0) flags[sr & 1] = 0;             // clear for reuse at sr+2
      __syncthreads();
      if (!cont) break;
    }
  }
  // reduce W_D (sum) and lmax (max), assemble output
  for (int off = 32; off >= 1; off >>= 1) {
    wD += __shfl_down(wD, off);
    lmax = fmaxf(lmax, __shfl_down(lmax, off));
  }
  if (lane == 0) { redS[tid >> 6] = wD; redM[tid >> 6] = lmax; }
  __syncthreads();
  if (tid == 0) {
    float s = 0.f, m = 0.f;
    for (int w = 0; w < 16; ++w) { s += redS[w]; m = fmaxf(m, redM[w]); }
    float wmst = accF[0] - s;                     // primal MST via tree-cotree duality
    float loss0 = wmst + accF[1] - funmap(accU[2]);
    float sum1 = accF[3] - s;                     // sum of dim-1 bars (closed form)
    out[0] = loss0 + sum1 - m;
  }
}

extern "C" void kernel_launch(void* const* d_in, const int* in_sizes, int n_in,
                              void* d_out, int out_size, void* d_ws, size_t ws_size,
                              hipStream_t stream) {
  const float* beta = (const float*)d_in[0];
  float* out = (float*)d_out;
  char* ws = (char*)d_ws;
  float* accF = (float*)(ws + OFF_ACC);
  u32*   accU = (u32*)(ws + OFF_ACC);
  u32* r32 = (u32*)(ws + OFF_R32);
  float* fval = (float*)(ws + OFF_FVAL);
  u16* ctv = (u16*)(ws + OFF_CTV);
  u32* cntR = (u32*)(ws + OFF_CNTR);
  u32* frk = (u32*)(ws + OFF_FRK);
  float* frv = (float*)(ws + OFF_FRV);
  float* dvals = (float*)(ws + OFF_DVAL);
  uint2* wlA = (uint2*)(ws + OFF_WLA);
  uint2* wlB = (uint2*)(ws + OFF_WLB);
  u32* rts = (u32*)(ws + OFF_RTS);

  hipLaunchKernelGGL(k_init, dim3(64), dim3(256), 0, stream, accF, r32);
  hipLaunchKernelGGL(k_rankv, dim3(64, 16), dim3(256), 0, stream, beta, r32);
  hipLaunchKernelGGL(k_build, dim3(191), dim3(256), 0, stream, beta, r32, fval, ctv, accF, accU);
  hipLaunchKernelGGL(k_cntface, dim3(64), dim3(256), 0, stream, ctv, r32, cntR);
  hipLaunchKernelGGL(k_scanR, dim3(1), dim3(1024), 0, stream, cntR);
  hipLaunchKernelGGL(k_facerank, dim3(127), dim3(256), 0, stream, ctv, r32, cntR, fval, frk, frv);
  hipLaunchKernelGGL(k_edges, dim3(191), dim3(256), 0, stream, beta, r32, frk, dvals, wlA, accF);
  hipLaunchKernelGGL(k_dual, dim3(1), dim3(1024), 0, stream, wlA, wlB, rts, dvals, frv, accF, accU, out);
}